// Round 1
// baseline (685.800 us; speedup 1.0000x reference)
//
#include <hip/hip_runtime.h>

#define THETA_DIM 11

typedef float v2f __attribute__((ext_vector_type(2)));

__device__ __forceinline__ v2f v2(float s) { return (v2f){s, s}; }

// Two independent chains per lane (b and b+B/2), step bodies interleaved so
// the second chain's ops fill the first chain's dependency-latency bubbles.
// Per-chain math is bit-identical to the previous (verified) kernel.
// Critical path per step (~50 cy latency) vs ~160 cy issue per 2 fused steps:
// issue-bound at ~80 cy/step instead of latency-bound ~196 cy/step.
__global__ void __launch_bounds__(64, 1)
bh_kernel(const float* __restrict__ theta, const float* __restrict__ eps,
          float* __restrict__ out, int Tn, int B) {
  const int lane = blockIdx.x * 64 + threadIdx.x;   // 0 .. B/2-1
  const int b0 = lane;
  const int b1 = lane + (B >> 1);

  const float L2E = 1.4426950408889634f;

  // ---- chain A constants ----
  const float* tha = theta + (size_t)b0 * THETA_DIM;
  const float beta_a = tha[0];
  const v2f g01a = {tha[1], tha[2]}, g23a = {tha[3], tha[4]};
  const v2f b01a = {tha[5], tha[6]}, b23a = {tha[7], tha[8]};
  const float sig_a = tha[9];
  const float Ra    = 1.0f + tha[10];
  const float invRa = 1.0f / Ra;
  const float bl2e_a  = beta_a * L2E;
  const float bl2eR_a = bl2e_a * Ra;
  const float sR_a    = sig_a * invRa;
  const v2f gR01a = g01a * v2(invRa), gR23a = g23a * v2(invRa);
  const v2f bR01a = b01a * v2(invRa), bR23a = b23a * v2(invRa);
  const v2f nRa   = v2(-Ra);

  // ---- chain B constants ----
  const float* thb = theta + (size_t)b1 * THETA_DIM;
  const float beta_b = thb[0];
  const v2f g01b = {thb[1], thb[2]}, g23b = {thb[3], thb[4]};
  const v2f b01b = {thb[5], thb[6]}, b23b = {thb[7], thb[8]};
  const float sig_b = thb[9];
  const float Rb    = 1.0f + thb[10];
  const float invRb = 1.0f / Rb;
  const float bl2e_b  = beta_b * L2E;
  const float bl2eR_b = bl2e_b * Rb;
  const float sR_b    = sig_b * invRb;
  const v2f gR01b = g01b * v2(invRb), gR23b = g23b * v2(invRb);
  const v2f bR01b = b01b * v2(invRb), bR23b = b23b * v2(invRb);
  const v2f nRb   = v2(-Rb);

  // ---- chain A state ----
  float x1a = 0.f, x2a = 0.f, m1a = 0.f;
  v2f q01a = b01a, q23a = b23a;
  v2f c01a = bR01a, c23a = bR23a;
  v2f qmma;
  {
    v2f mx = __builtin_elementwise_max(q01a, q23a);
    v2f mn = __builtin_elementwise_min(q01a, q23a);
    qmma = (v2f){fmaxf(mx.x, mx.y), fminf(mn.x, mn.y)};
  }
  // ---- chain B state ----
  float x1b = 0.f, x2b = 0.f, m1b = 0.f;
  v2f q01b = b01b, q23b = b23b;
  v2f c01b = bR01b, c23b = bR23b;
  v2f qmmb;
  {
    v2f mx = __builtin_elementwise_max(q01b, q23b);
    v2f mn = __builtin_elementwise_min(q01b, q23b);
    qmmb = (v2f){fmaxf(mx.x, mx.y), fminf(mn.x, mn.y)};
  }

  // Fused double step: both chains, statements interleaved.
  auto step2 = [&](float ea, float eb, float& xa_out, float& xb_out) {
    // ---- on-path ----
    const float Aa = fmaf(bl2e_a, x1a, -m1a);
    const float Ab = fmaf(bl2e_b, x1b, -m1b);
    const v2f  uva = v2(Aa) * qmma;
    const v2f  uvb = v2(Ab) * qmmb;
    const float ma = fmaxf(uva.x, uva.y);
    const float mb = fmaxf(uvb.x, uvb.y);
    const v2f  e01a = __builtin_elementwise_fma(v2(Aa), q01a, v2(-ma));
    const v2f  e23a = __builtin_elementwise_fma(v2(Aa), q23a, v2(-ma));
    const v2f  e01b = __builtin_elementwise_fma(v2(Ab), q01b, v2(-mb));
    const v2f  e23b = __builtin_elementwise_fma(v2(Ab), q23b, v2(-mb));
    const v2f  p01a = {__builtin_amdgcn_exp2f(e01a.x), __builtin_amdgcn_exp2f(e01a.y)};
    const v2f  p23a = {__builtin_amdgcn_exp2f(e23a.x), __builtin_amdgcn_exp2f(e23a.y)};
    const v2f  p01b = {__builtin_amdgcn_exp2f(e01b.x), __builtin_amdgcn_exp2f(e01b.y)};
    const v2f  p23b = {__builtin_amdgcn_exp2f(e23b.x), __builtin_amdgcn_exp2f(e23b.y)};
    // ---- off-path: next-step precompute from pre-shift state ----
    const v2f  w01a  = __builtin_elementwise_fma(g01a, v2(x2a), b01a);
    const v2f  w23a  = __builtin_elementwise_fma(g23a, v2(x2a), b23a);
    const v2f  w01b  = __builtin_elementwise_fma(g01b, v2(x2b), b01b);
    const v2f  w23b  = __builtin_elementwise_fma(g23b, v2(x2b), b23b);
    const v2f  q01na = __builtin_elementwise_fma(nRa, v2(x1a), w01a);
    const v2f  q23na = __builtin_elementwise_fma(nRa, v2(x1a), w23a);
    const v2f  q01nb = __builtin_elementwise_fma(nRb, v2(x1b), w01b);
    const v2f  q23nb = __builtin_elementwise_fma(nRb, v2(x1b), w23b);
    const v2f  mxva  = __builtin_elementwise_max(q01na, q23na);
    const v2f  mnva  = __builtin_elementwise_min(q01na, q23na);
    const v2f  mxvb  = __builtin_elementwise_max(q01nb, q23nb);
    const v2f  mnvb  = __builtin_elementwise_min(q01nb, q23nb);
    const float m1na = bl2eR_a * x1a;
    const float m1nb = bl2eR_b * x1b;
    // ---- on-path finish ----
    const v2f  nva  = __builtin_elementwise_fma(p23a, c23a, p01a * c01a);
    const v2f  nvb  = __builtin_elementwise_fma(p23b, c23b, p01b * c01b);
    const float numa = nva.x + nva.y;
    const float numb = nvb.x + nvb.y;
    const v2f  dva  = p01a + p23a;
    const v2f  dvb  = p01b + p23b;
    const float dena = dva.x + dva.y;
    const float denb = dvb.x + dvb.y;
    const float xa = fmaf(numa, __builtin_amdgcn_rcpf(dena), ea * sR_a);
    const float xb = fmaf(numb, __builtin_amdgcn_rcpf(denb), eb * sR_b);
    // ---- shift + next-step c ----
    x2a = x1a; x1a = xa;
    x2b = x1b; x1b = xb;
    m1a = m1na; q01a = q01na; q23a = q23na;
    m1b = m1nb; q01b = q01nb; q23b = q23nb;
    qmma = (v2f){fmaxf(mxva.x, mxva.y), fminf(mnva.x, mnva.y)};
    qmmb = (v2f){fmaxf(mxvb.x, mxvb.y), fminf(mnvb.x, mnvb.y)};
    c01a = __builtin_elementwise_fma(gR01a, v2(xa), bR01a);
    c23a = __builtin_elementwise_fma(gR23a, v2(xa), bR23a);
    c01b = __builtin_elementwise_fma(gR01b, v2(xb), bR01b);
    c23b = __builtin_elementwise_fma(gR23b, v2(xb), bR23b);
    xa_out = xa; xb_out = xb;
  };

  const float* epa = eps + (size_t)b0 * Tn;
  const float* epb = eps + (size_t)b1 * Tn;
  float* opa = out + (size_t)b0 * Tn;
  float* opb = out + (size_t)b1 * Tn;

  // eps register pipeline: 16-float blocks per chain, 1 block ahead
  // (~16 fused steps ≈ 2500 cy of cover vs ~900 cy HBM latency).
  float4 curA[4], curB[4], nxtA[4], nxtB[4];
  #pragma unroll
  for (int i = 0; i < 4; ++i) {
    curA[i] = *(const float4*)(epa + i * 4);
    curB[i] = *(const float4*)(epb + i * 4);
  }

  const int NB = Tn / 16;
  int t0 = 0;
  for (int blk = 0; blk < NB; ++blk) {
    int tl = t0 + 16;
    if (tl > Tn - 16) tl = Tn - 16;
    #pragma unroll
    for (int i = 0; i < 4; ++i) {
      nxtA[i] = *(const float4*)(epa + tl + i * 4);
      nxtB[i] = *(const float4*)(epb + tl + i * 4);
    }

    #pragma unroll
    for (int i = 0; i < 4; ++i) {
      float4 oA, oB;
      step2(curA[i].x, curB[i].x, oA.x, oB.x);
      step2(curA[i].y, curB[i].y, oA.y, oB.y);
      step2(curA[i].z, curB[i].z, oA.z, oB.z);
      step2(curA[i].w, curB[i].w, oA.w, oB.w);
      *(float4*)(opa + t0 + i * 4) = oA;   // per-lane row store; L2 write-combines
      *(float4*)(opb + t0 + i * 4) = oB;
    }

    #pragma unroll
    for (int i = 0; i < 4; ++i) { curA[i] = nxtA[i]; curB[i] = nxtB[i]; }
    t0 += 16;
  }
}

extern "C" void kernel_launch(void* const* d_in, const int* in_sizes, int n_in,
                              void* d_out, int out_size, void* d_ws, size_t ws_size,
                              hipStream_t stream) {
  const float* theta = (const float*)d_in[0];
  const float* eps   = (const float*)d_in[1];
  float* out = (float*)d_out;
  const int B  = in_sizes[0] / THETA_DIM;   // 8192
  const int Tn = in_sizes[1] / B;           // 4096
  const int blocks = (B / 2) / 64;          // 64 blocks, 2 chains per lane
  bh_kernel<<<blocks, 64, 0, stream>>>(theta, eps, out, Tn, B);
}

// Round 2
// 475.521 us; speedup vs baseline: 1.4422x; 1.4422x over previous
//
#include <hip/hip_runtime.h>

#define THETA_DIM 11

// Intra-quad butterfly permutes via DPP (full-rate VALU, no LDS, compiler
// inserts the required hazard wait-states for v_mov_b32_dpp).
// quad_perm:[1,0,3,2] = xor1 -> ctrl 0xB1 ; quad_perm:[2,3,0,1] = xor2 -> 0x4E.
__device__ __forceinline__ float dpp_xor1(float v) {
  return __builtin_bit_cast(float,
    __builtin_amdgcn_update_dpp(0, __builtin_bit_cast(int, v), 0xB1, 0xF, 0xF, true));
}
__device__ __forceinline__ float dpp_xor2(float v) {
  return __builtin_bit_cast(float,
    __builtin_amdgcn_update_dpp(0, __builtin_bit_cast(int, v), 0x4E, 0xF, 0xF, true));
}

// 4 lanes per chain (component j in lane 4c+j), 16 chains per wave.
// 8192 chains -> 512 waves over 1024 SIMDs: 4x the issue ports of the
// 1-chain/lane layout, ~1/4 the per-lane issue per step. Softmax reductions
// (max_j, sum p, sum p*c) are intra-quad DPP butterflies; all 4 lanes end
// each step with bit-identical x (butterfly is symmetric), so chain state
// stays coherent across the quad with no broadcast.
__global__ void __launch_bounds__(64, 1)
bh_kernel(const float* __restrict__ theta, const float* __restrict__ eps,
          float* __restrict__ out, int Tn) {
  const int tid = threadIdx.x;
  const int chain = blockIdx.x * 16 + (tid >> 2);
  const int j = tid & 3;

  const float* th = theta + (size_t)chain * THETA_DIM;
  const float beta = th[0];
  const float g  = th[1 + j];
  const float bb = th[5 + j];
  const float sig = th[9];
  const float R   = 1.0f + th[10];
  const float invR = 1.0f / R;
  const float L2E  = 1.4426950408889634f;
  const float bl2e  = beta * L2E;
  const float bl2eR = bl2e * R;
  const float sR    = sig * invR;
  const float gR = g * invR, bR = bb * invR;
  const float nR = -R;

  // state (x1=x2=x3=0); x1/x2/m1 are chain-wide (computed redundantly in all
  // 4 lanes), q/c are the lane's component.
  float x1 = 0.f, x2 = 0.f;
  float m1 = 0.f;            // bl2eR * x2
  float q  = bb;             // g*x3 + b - R*x2
  float c  = bR;             // (g*x1 + b)/R
  float qmax, qmin;
  {
    float t  = dpp_xor1(q);
    float mx = fmaxf(q, t), mn = fminf(q, t);
    qmax = fmaxf(mx, dpp_xor2(mx));
    qmin = fminf(mn, dpp_xor2(mn));
  }

  auto step = [&](float e) -> float {
    // ---- on-path ----
    const float A  = fmaf(bl2e, x1, -m1);        // beta*l2e*(x1 - R*x2)
    const float m  = fmaxf(A * qmax, A * qmin);  // = max_j(A*q_j), branchless
    const float eo = fmaf(A, q, -m);
    const float p  = __builtin_amdgcn_exp2f(eo);
    const float pc = p * c;
    // quad butterfly: all 4 lanes get full sums (bit-identical)
    float den = p  + dpp_xor1(p);
    float num = pc + dpp_xor1(pc);
    den += dpp_xor2(den);
    num += dpp_xor2(num);
    // ---- off-path: next-step q and its quad max/min from pre-shift state ----
    const float w  = fmaf(g, x2, bb);            // g*x3' + b
    const float qn = fmaf(nR, x1, w);            // - R*x2'
    float t  = dpp_xor1(qn);
    float mx = fmaxf(qn, t), mn = fminf(qn, t);
    mx = fmaxf(mx, dpp_xor2(mx));
    mn = fminf(mn, dpp_xor2(mn));
    const float m1n = bl2eR * x1;
    // ---- on-path finish ----
    const float x = fmaf(num, __builtin_amdgcn_rcpf(den), e * sR);
    // ---- shift ----
    x2 = x1; x1 = x;
    q = qn; qmax = mx; qmin = mn; m1 = m1n;
    c = fmaf(gR, x, bR);
    return x;
  };

  const float* ep = eps + (size_t)chain * Tn;   // all 4 quad lanes read same row
  float* op = out + (size_t)chain * Tn;
  const bool writer = (j == 0);

  // eps register pipeline: 16-float blocks, 2 blocks (~32 steps) deep.
  float4 cA[4], cB[4], cC[4];
  #pragma unroll
  for (int i = 0; i < 4; ++i) cA[i] = *(const float4*)(ep + i * 4);
  #pragma unroll
  for (int i = 0; i < 4; ++i) cB[i] = *(const float4*)(ep + 16 + i * 4);

  const int NB = Tn / 16;
  int t0 = 0;
  for (int blk = 0; blk < NB; ++blk) {
    int tl = t0 + 32;
    if (tl > Tn - 16) tl = Tn - 16;
    const float* lp = ep + tl;
    #pragma unroll
    for (int i = 0; i < 4; ++i) cC[i] = *(const float4*)(lp + i * 4);

    #pragma unroll
    for (int i = 0; i < 4; ++i) {
      float4 o;
      o.x = step(cA[i].x);
      o.y = step(cA[i].y);
      o.z = step(cA[i].z);
      o.w = step(cA[i].w);
      if (writer) *(float4*)(op + t0 + i * 4) = o;  // one lane per chain stores
    }

    #pragma unroll
    for (int i = 0; i < 4; ++i) { cA[i] = cB[i]; cB[i] = cC[i]; }
    t0 += 16;
  }
}

extern "C" void kernel_launch(void* const* d_in, const int* in_sizes, int n_in,
                              void* d_out, int out_size, void* d_ws, size_t ws_size,
                              hipStream_t stream) {
  const float* theta = (const float*)d_in[0];
  const float* eps   = (const float*)d_in[1];
  float* out = (float*)d_out;
  const int B  = in_sizes[0] / THETA_DIM;   // 8192
  const int Tn = in_sizes[1] / B;           // 4096
  const int blocks = B / 16;                // 512 waves: 16 chains x 4 lanes each
  bh_kernel<<<blocks, 64, 0, stream>>>(theta, eps, out, Tn);
}